// Round 1
// baseline (421.192 us; speedup 1.0000x reference)
//
#include <hip/hip_runtime.h>
#include <stdint.h>

typedef __attribute__((ext_vector_type(8))) short short8;
typedef __attribute__((ext_vector_type(4))) float floatx4;

#define B_DIM 8192
#define K_DIM 2048
#define N_DIM 2048

// round-to-nearest-even fp32 -> bf16
__device__ __forceinline__ unsigned short f2bf(float f) {
    union { float f; unsigned u; } v; v.f = f;
    unsigned r = v.u + 0x7fffu + ((v.u >> 16) & 1u);
    return (unsigned short)(r >> 16);
}

__device__ __forceinline__ void gld_lds16(const void* g, void* l) {
    __builtin_amdgcn_global_load_lds(
        (const __attribute__((address_space(1))) void*)g,
        (__attribute__((address_space(3))) void*)l, 16, 0, 0);
}

// ---------------- prepass 1: X -> Xb (bf16), Lb = bf16(log(|x|+eps)) ----------------
__global__ __launch_bounds__(256) void prep_x(const float4* __restrict__ X4,
                                              ushort* __restrict__ Xb,
                                              ushort* __restrict__ Lb) {
    int i = blockIdx.x * 256 + threadIdx.x;
    float4 v = X4[i];
    ushort4 xb, lb;
    xb.x = f2bf(v.x); xb.y = f2bf(v.y); xb.z = f2bf(v.z); xb.w = f2bf(v.w);
    lb.x = f2bf(__logf(fabsf(v.x) + 1e-7f));
    lb.y = f2bf(__logf(fabsf(v.y) + 1e-7f));
    lb.z = f2bf(__logf(fabsf(v.z) + 1e-7f));
    lb.w = f2bf(__logf(fabsf(v.w) + 1e-7f));
    *(ushort4*)(Xb + (size_t)i * 4) = xb;
    *(ushort4*)(Lb + (size_t)i * 4) = lb;
}

// ---------------- prepass 2: Wt[n][k] = bf16(tanh(Wh)*sigmoid(Mh)), Gt[n][k] = bf16(gate) ----
__global__ __launch_bounds__(256) void prep_wg(const float* __restrict__ Wh,
                                               const float* __restrict__ Mh,
                                               const float* __restrict__ Gf,
                                               ushort* __restrict__ Wt,
                                               ushort* __restrict__ Gt) {
    __shared__ float tw[32][33];
    __shared__ float tg[32][33];
    const int k0 = blockIdx.y * 32, n0 = blockIdx.x * 32;
    const int tx = threadIdx.x, ty = threadIdx.y;  // 32 x 8
#pragma unroll
    for (int i = 0; i < 4; i++) {
        int k = k0 + ty + i * 8;
        int n = n0 + tx;
        size_t idx = (size_t)k * N_DIM + n;
        float wh = Wh[idx], mh = Mh[idx];
        tw[ty + i * 8][tx] = tanhf(wh) * (1.f / (1.f + __expf(-mh)));
        tg[ty + i * 8][tx] = Gf[idx];
    }
    __syncthreads();
#pragma unroll
    for (int i = 0; i < 4; i++) {
        int n = n0 + ty + i * 8;
        int k = k0 + tx;
        Wt[(size_t)n * K_DIM + k] = f2bf(tw[tx][ty + i * 8]);
        Gt[(size_t)n * K_DIM + k] = f2bf(tg[tx][ty + i * 8]);
    }
}

// ---------------- fused GEMM: a = Xb@Wt^T, lm = Lb@Wt^T, gl = Xb@Gt^T ----------------
// out = sigmoid(gl)*a + (1-sigmoid(gl))*exp(lm)
// 128x128 block tile, 4 waves (2x2), 64x64 per wave per acc set, BK=32.
//
// Round-N changes vs 359us baseline:
//  (1) T2 XOR bank-swizzle: LDS rows are 64B; the fragment read pattern
//      (lane&15 -> row, lane>>4 -> 16B chunk) was a ~4-way bank conflict on
//      EVERY ds_read_b128 (rows at 64B stride alias to 2 of 8 bank-quads).
//      Fix per rule #21: keep gld_lds dest LINEAR, permute the GLOBAL source
//      per-thread by the swizzle inverse, XOR the read address with
//      ((row&7)<<4). Bijective (bit6 of the mask folds into the row-parity
//      bit; inverse is r = 2*(d>>7) | ((d>>6)^(d>>8))&1, c = (d>>4&3)^(r&3)).
//  (2) Minimal 2-phase prefetch: double-buffered LDS (2 x 32KB), next K-step's
//      8 global_load_lds issued BEFORE current compute, one vmcnt(0)+barrier
//      per K-step (was: stage -> drain -> compute, latency fully exposed).
// LDS stays ONE shared object (cross-section offsets legal only within one
// object — the old four-array version read garbage and produced NaN).
#define SEC  (128 * 32)        // elems per section (8 KB)
#define BUFE (4 * SEC)         // elems per buffer  (32 KB)

__global__ __launch_bounds__(256, 2) void gemm_fused(const ushort* __restrict__ Xb,
                                                     const ushort* __restrict__ Lb,
                                                     const ushort* __restrict__ Wt,
                                                     const ushort* __restrict__ Gt,
                                                     float* __restrict__ out) {
    __shared__ ushort smem[2 * BUFE];
    ushort* s0 = smem;
    ushort* s1 = smem + BUFE;

    const int t = threadIdx.x;
    const int lane = t & 63;
    const int w = t >> 6;
    const int wm = w >> 1, wn = w & 1;
    const int rowA = blockIdx.y * 128;   // M tile base
    const int rowB = blockIdx.x * 128;   // N tile base

    floatx4 acca[4][4], accm[4][4], accg[4][4];
    const floatx4 z = {0.f, 0.f, 0.f, 0.f};
#pragma unroll
    for (int i = 0; i < 4; i++)
#pragma unroll
        for (int j = 0; j < 4; j++) { acca[i][j] = z; accm[i][j] = z; accg[i][j] = z; }

    // ---- staging: swizzle-inverse source coordinates -------------------------
    // dest byte d (linear, = thread*16) holds global (r,c) with
    // d == (r*64 + c*16) ^ ((r&7)<<4).
    const int d0 = t * 16;
    const int d1 = (t + 256) * 16;
    const int r0 = ((d0 >> 7) << 1) | (((d0 >> 6) ^ (d0 >> 8)) & 1);
    const int c0 = ((d0 >> 4) & 3) ^ (r0 & 3);
    const int r1 = ((d1 >> 7) << 1) | (((d1 >> 6) ^ (d1 >> 8)) & 1);
    const int c1 = ((d1 >> 4) & 3) ^ (r1 & 3);
    const int ga0 = (rowA + r0) * K_DIM + c0 * 8;
    const int ga1 = (rowA + r1) * K_DIM + c1 * 8;
    const int gb0 = (rowB + r0) * K_DIM + c0 * 8;
    const int gb1 = (rowB + r1) * K_DIM + c1 * 8;
    const int e0 = t * 8, e1 = (t + 256) * 8;   // linear dest (elems)

#define STAGE(sb, k0) do {                                   \
    gld_lds16(Xb + ga0 + (k0), (sb) + e0);                   \
    gld_lds16(Xb + ga1 + (k0), (sb) + e1);                   \
    gld_lds16(Lb + ga0 + (k0), (sb) + SEC + e0);             \
    gld_lds16(Lb + ga1 + (k0), (sb) + SEC + e1);             \
    gld_lds16(Wt + gb0 + (k0), (sb) + 2 * SEC + e0);         \
    gld_lds16(Wt + gb1 + (k0), (sb) + 2 * SEC + e1);         \
    gld_lds16(Gt + gb0 + (k0), (sb) + 3 * SEC + e0);         \
    gld_lds16(Gt + gb1 + (k0), (sb) + 3 * SEC + e1);         \
} while (0)

    // ---- fragment read bases (byte offsets, swizzled) ------------------------
    const int lr = lane & 15;
    const int rbA = (((wm * 64 + lr) * 64) + ((lane >> 4) * 16)) ^ ((lr & 7) << 4);
    const int rbB = (((wn * 64 + lr) * 64) + ((lane >> 4) * 16)) ^ ((lr & 7) << 4);
    // per-mi/ni offsets are +mi*1024B (16 rows) — bits >=10, no swizzle overlap;
    // cross-section offset +SEC*2 bytes likewise.

#define COMPUTE(sb) do {                                                        \
    const char* bA = (const char*)(sb) + rbA;                                   \
    const char* bB = (const char*)(sb) + 2 * SEC * 2 + rbB;                     \
    short8 bw[4], bg[4];                                                        \
    _Pragma("unroll")                                                           \
    for (int ni = 0; ni < 4; ni++) {                                            \
        bw[ni] = *(const short8*)(bB + ni * 1024);                              \
        bg[ni] = *(const short8*)(bB + SEC * 2 + ni * 1024);                    \
    }                                                                           \
    _Pragma("unroll")                                                           \
    for (int mi = 0; mi < 4; mi++) {                                            \
        short8 ax = *(const short8*)(bA + mi * 1024);                           \
        short8 al = *(const short8*)(bA + SEC * 2 + mi * 1024);                 \
        _Pragma("unroll")                                                       \
        for (int ni = 0; ni < 4; ni++) {                                        \
            acca[mi][ni] = __builtin_amdgcn_mfma_f32_16x16x32_bf16(ax, bw[ni], acca[mi][ni], 0, 0, 0); \
            accm[mi][ni] = __builtin_amdgcn_mfma_f32_16x16x32_bf16(al, bw[ni], accm[mi][ni], 0, 0, 0); \
            accg[mi][ni] = __builtin_amdgcn_mfma_f32_16x16x32_bf16(ax, bg[ni], accg[mi][ni], 0, 0, 0); \
        }                                                                       \
    }                                                                           \
} while (0)

#define VMCNT0() asm volatile("s_waitcnt vmcnt(0)" ::: "memory")
#define MEMFENCE() asm volatile("" ::: "memory")

    // prologue: fill buffer 0
    STAGE(s0, 0);
    VMCNT0();
    __syncthreads();

    for (int k0 = 0; k0 < K_DIM; k0 += 64) {
        STAGE(s1, k0 + 32);          // prefetch next K-step into buf1
        MEMFENCE();                  // keep prefetch issue ahead of compute
        COMPUTE(s0);
        VMCNT0();
        __syncthreads();
        if (k0 + 64 < K_DIM) STAGE(s0, k0 + 64);
        MEMFENCE();
        COMPUTE(s1);
        VMCNT0();
        __syncthreads();
    }

    const int rsub = (lane >> 4) << 2;
#pragma unroll
    for (int mi = 0; mi < 4; mi++)
#pragma unroll
        for (int ni = 0; ni < 4; ni++)
#pragma unroll
            for (int r = 0; r < 4; r++) {
                int row = rowA + wm * 64 + mi * 16 + rsub + r;
                int col = rowB + wn * 64 + ni * 16 + lr;
                float g = 1.f / (1.f + __expf(-accg[mi][ni][r]));
                float a = acca[mi][ni][r];
                float m = __expf(accm[mi][ni][r]);
                out[(size_t)row * N_DIM + col] = g * a + (1.f - g) * m;
            }
}

extern "C" void kernel_launch(void* const* d_in, const int* in_sizes, int n_in,
                              void* d_out, int out_size, void* d_ws, size_t ws_size,
                              hipStream_t stream) {
    const float* X  = (const float*)d_in[0];
    const float* Wh = (const float*)d_in[1];
    const float* Mh = (const float*)d_in[2];
    const float* Gf = (const float*)d_in[3];
    float* out = (float*)d_out;

    // workspace layout (bytes):
    //   Xb : B*K*2  = 33,554,432
    //   Lb : B*K*2  = 33,554,432
    //   Wt : N*K*2  =  8,388,608   (transposed: [n][k])
    //   Gt : N*K*2  =  8,388,608
    char* ws = (char*)d_ws;
    ushort* Xb = (ushort*)(ws);
    ushort* Lb = (ushort*)(ws + (size_t)B_DIM * K_DIM * 2);
    ushort* Wt = (ushort*)(ws + (size_t)B_DIM * K_DIM * 4);
    ushort* Gt = (ushort*)(ws + (size_t)B_DIM * K_DIM * 4 + (size_t)N_DIM * K_DIM * 2);

    prep_x<<<dim3((B_DIM * K_DIM) / (256 * 4)), dim3(256), 0, stream>>>(
        (const float4*)X, Xb, Lb);

    prep_wg<<<dim3(N_DIM / 32, K_DIM / 32), dim3(32, 8), 0, stream>>>(Wh, Mh, Gf, Wt, Gt);

    gemm_fused<<<dim3(N_DIM / 128, B_DIM / 128), dim3(256), 0, stream>>>(Xb, Lb, Wt, Gt, out);
}